// Round 2
// baseline (1326.095 us; speedup 1.0000x reference)
//
#include <hip/hip_runtime.h>

typedef unsigned int uint32;
typedef unsigned short u16;
typedef __attribute__((ext_vector_type(4))) float f32x4;
typedef __attribute__((ext_vector_type(8))) short bf16x8;

#define HID 1024
#define NTOK 32768  // B*S = 4*8192

// ---------- bf16 helpers (RNE, raw bits; inputs are finite) ----------
__device__ __forceinline__ u16 f2bf(float f) {
    uint32 u = __builtin_bit_cast(uint32, f);
    u += 0x7FFFu + ((u >> 16) & 1u);
    return (u16)(u >> 16);
}
__device__ __forceinline__ float bf2f(u16 h) {
    uint32 u = ((uint32)h) << 16;
    return __builtin_bit_cast(float, u);
}

// async global->LDS, 16B per lane, LDS dest = wave-uniform base + lane*16
__device__ __forceinline__ void async16(const void* g, void* l) {
    __builtin_amdgcn_global_load_lds(
        (const __attribute__((address_space(1))) uint32*)g,
        (__attribute__((address_space(3))) uint32*)l, 16, 0, 0);
}

// ---------- fp32 -> (hi,lo) bf16 split, 4 elems/thread ----------
__global__ __launch_bounds__(256) void split_kernel(const float* __restrict__ x,
                                                    u16* __restrict__ hi,
                                                    u16* __restrict__ lo,
                                                    int n) {
    int i = (blockIdx.x * 256 + threadIdx.x) * 4;
    if (i >= n) return;
    float4 v = *reinterpret_cast<const float4*>(x + i);
    u16 h0 = f2bf(v.x), h1 = f2bf(v.y), h2 = f2bf(v.z), h3 = f2bf(v.w);
    u16 l0 = f2bf(v.x - bf2f(h0)), l1 = f2bf(v.y - bf2f(h1));
    u16 l2 = f2bf(v.z - bf2f(h2)), l3 = f2bf(v.w - bf2f(h3));
    *reinterpret_cast<uint2*>(hi + i) =
        make_uint2((uint32)h0 | ((uint32)h1 << 16), (uint32)h2 | ((uint32)h3 << 16));
    *reinterpret_cast<uint2*>(lo + i) =
        make_uint2((uint32)l0 | ((uint32)l1 << 16), (uint32)l2 | ((uint32)l3 << 16));
}

// ---------- split-bf16 GEMM: C[m,n] = sum_k A[m,k]*W[n,k] (fp32 out) ----------
// A: [M][1024] hi/lo bf16, W: [1024][1024] hi/lo bf16 (row n = output col n)
// 128x128 tile, BK=32, 4 waves, each wave 64x64 (4x4 frags of 16x16x32 MFMA)
__device__ __forceinline__ void gemm_body(const u16* __restrict__ Ahi,
                                          const u16* __restrict__ Alo,
                                          const u16* __restrict__ Bhi,
                                          const u16* __restrict__ Blo,
                                          float* __restrict__ C) {
    __shared__ u16 sAh[128 * 32], sAl[128 * 32], sBh[128 * 32], sBl[128 * 32];
    const int tid = threadIdx.x;
    const int wave = tid >> 6, lane = tid & 63;
    const int m0 = blockIdx.x * 128, n0 = blockIdx.y * 128;
    const int wm = (wave >> 1) * 64, wn = (wave & 1) * 64;
    const int srow = lane >> 2;        // 0..15 (staging row within 16-row segment)
    const int scol = (lane & 3) * 8;   // 0,8,16,24 (element offset of 16B chunk)
    const int fr = lane & 15;          // fragment row/col
    const int kg = (lane >> 4) * 8;    // fragment k-group

    f32x4 acc[4][4];
#pragma unroll
    for (int a = 0; a < 4; a++)
#pragma unroll
        for (int b = 0; b < 4; b++) acc[a][b] = f32x4{0.f, 0.f, 0.f, 0.f};

    for (int k0 = 0; k0 < HID; k0 += 32) {
        // stage 4 tiles (A hi/lo, B hi/lo), each 128x32 bf16; wave w does segments 2w,2w+1
#pragma unroll
        for (int i = 0; i < 2; i++) {
            const int seg = wave * 2 + i;
            const int r = seg * 16 + srow;
            const size_t ga = (size_t)(m0 + r) * HID + k0 + scol;
            const size_t gb = (size_t)(n0 + r) * HID + k0 + scol;
            async16(Ahi + ga, &sAh[seg * 512]);
            async16(Alo + ga, &sAl[seg * 512]);
            async16(Bhi + gb, &sBh[seg * 512]);
            async16(Blo + gb, &sBl[seg * 512]);
        }
        __syncthreads();  // drains vmcnt per guide, then barrier

        bf16x8 fah[4], fal[4], fbh[4], fbl[4];
#pragma unroll
        for (int a = 0; a < 4; a++) {
            const int row = wm + a * 16 + fr;
            fah[a] = *reinterpret_cast<const bf16x8*>(&sAh[row * 32 + kg]);
            fal[a] = *reinterpret_cast<const bf16x8*>(&sAl[row * 32 + kg]);
        }
#pragma unroll
        for (int b = 0; b < 4; b++) {
            const int row = wn + b * 16 + fr;
            fbh[b] = *reinterpret_cast<const bf16x8*>(&sBh[row * 32 + kg]);
            fbl[b] = *reinterpret_cast<const bf16x8*>(&sBl[row * 32 + kg]);
        }
        // product 1: Ahi*Bhi
#pragma unroll
        for (int a = 0; a < 4; a++)
#pragma unroll
            for (int b = 0; b < 4; b++)
                acc[a][b] = __builtin_amdgcn_mfma_f32_16x16x32_bf16(fah[a], fbh[b], acc[a][b], 0, 0, 0);
        // product 2: Ahi*Blo
#pragma unroll
        for (int a = 0; a < 4; a++)
#pragma unroll
            for (int b = 0; b < 4; b++)
                acc[a][b] = __builtin_amdgcn_mfma_f32_16x16x32_bf16(fah[a], fbl[b], acc[a][b], 0, 0, 0);
        // product 3: Alo*Bhi
#pragma unroll
        for (int a = 0; a < 4; a++)
#pragma unroll
            for (int b = 0; b < 4; b++)
                acc[a][b] = __builtin_amdgcn_mfma_f32_16x16x32_bf16(fal[a], fbh[b], acc[a][b], 0, 0, 0);
        __syncthreads();
    }

    // epilogue: D col = lane&15, row = (lane>>4)*4 + j  [verified m89/m91]
    const int col = lane & 15, r0 = (lane >> 4) * 4;
#pragma unroll
    for (int a = 0; a < 4; a++)
#pragma unroll
        for (int b = 0; b < 4; b++)
#pragma unroll
            for (int j = 0; j < 4; j++)
                C[(size_t)(m0 + wm + a * 16 + r0 + j) * HID + (n0 + wn + b * 16 + col)] =
                    acc[a][b][j];
}

__global__ __launch_bounds__(256) void gemm_qkv(
    const u16* __restrict__ xhi, const u16* __restrict__ xlo,
    const u16* __restrict__ w0h, const u16* __restrict__ w0l,
    const u16* __restrict__ w1h, const u16* __restrict__ w1l,
    const u16* __restrict__ w2h, const u16* __restrict__ w2l,
    float* __restrict__ q, float* __restrict__ k, float* __restrict__ v) {
    const u16 *bh, *bl;
    float* c;
    if (blockIdx.z == 0)      { bh = w0h; bl = w0l; c = q; }
    else if (blockIdx.z == 1) { bh = w1h; bl = w1l; c = k; }
    else                      { bh = w2h; bl = w2l; c = v; }
    gemm_body(xhi, xlo, bh, bl, c);
}

__global__ __launch_bounds__(256) void gemm_one(
    const u16* __restrict__ ahi, const u16* __restrict__ alo,
    const u16* __restrict__ bh, const u16* __restrict__ bl,
    float* __restrict__ c) {
    gemm_body(ahi, alo, bh, bl, c);
}

// ---------- per-token 32x32 attention (fp32), masks fused, writes attn hi/lo bf16 ----------
// 4 waves/block, 1 token/wave. Lane = 2*h + half; half covers 16 t (scores) / 16 d (PV).
__global__ __launch_bounds__(256) void attn_kernel(
    const float* __restrict__ Q, const float* __restrict__ K, const float* __restrict__ V,
    const float* __restrict__ mu_q, const float* __restrict__ sigma_q,
    const float* __restrict__ mu_kv, const float* __restrict__ sigma_kv,
    const float* __restrict__ eps_q, const float* __restrict__ eps_kv,
    u16* __restrict__ Ohi, u16* __restrict__ Olo) {
    // mat 0: q (reused as softmax weights after q consumed), 1: k, 2: v
    __shared__ float sm[4][3][32 * 33];
    __shared__ float mq[32], mkv[32];
    const int tid = threadIdx.x, wave = tid >> 6, lane = tid & 63;

    if (tid < 32) {
        mq[tid] = 1.f / (1.f + __expf(-(mu_q[tid] + eps_q[tid] * sigma_q[tid])));
    } else if (tid < 64) {
        const int d = tid - 32;
        mkv[d] = 1.f / (1.f + __expf(-(mu_kv[d] + eps_kv[d] * sigma_kv[d])));
    }
    __syncthreads();

    const size_t T = (size_t)blockIdx.x * 4 + wave;
    const float* src0 = Q + T * HID;
    const float* src1 = K + T * HID;
    const float* src2 = V + T * HID;
#pragma unroll
    for (int m = 0; m < 3; m++) {
        const float* s = (m == 0) ? src0 : (m == 1) ? src1 : src2;
        const float* msk = (m == 0) ? mq : mkv;
#pragma unroll
        for (int i = 0; i < 4; i++) {
            const int e = (i * 64 + lane) * 4;
            float4 v4 = *reinterpret_cast<const float4*>(s + e);
            const int r = e >> 5, c = e & 31;
            float* dst = &sm[wave][m][r * 33 + c];
            dst[0] = v4.x * msk[c];
            dst[1] = v4.y * msk[c + 1];
            dst[2] = v4.z * msk[c + 2];
            dst[3] = v4.w * msk[c + 3];
        }
    }
    __syncthreads();

    const int h = lane >> 1, half = lane & 1;
    // q row into registers (then sm[wave][0] is reusable for weights)
    float qreg[32];
    const float* qr = &sm[wave][0][h * 33];
#pragma unroll
    for (int d = 0; d < 32; d++) qreg[d] = qr[d];

    // scores for 16 t's
    float sc[16];
    const float* kr = &sm[wave][1][0];
#pragma unroll
    for (int t1 = 0; t1 < 16; t1++) {
        const int t = half * 16 + t1;
        float a = 0.f;
#pragma unroll
        for (int d = 0; d < 32; d++) a += qreg[d] * kr[t * 33 + d];
        sc[t1] = a * 0.17677669529663687f;  // 1/sqrt(32)
    }
    // softmax over 32 t (2 lanes per row)
    float mx = sc[0];
#pragma unroll
    for (int t1 = 1; t1 < 16; t1++) mx = fmaxf(mx, sc[t1]);
    mx = fmaxf(mx, __shfl_xor(mx, 1));
    float sum = 0.f;
#pragma unroll
    for (int t1 = 0; t1 < 16; t1++) {
        sc[t1] = __expf(sc[t1] - mx);
        sum += sc[t1];
    }
    sum += __shfl_xor(sum, 1);
    const float inv = 1.f / sum;
    float* wrow = &sm[wave][0][h * 33];
#pragma unroll
    for (int t1 = 0; t1 < 16; t1++) wrow[half * 16 + t1] = sc[t1] * inv;
    __syncthreads();

    // PV: attn[h][d] = sum_t w[h][t] * v[t][d], this lane: d in [half*16, half*16+16)
    float acc[16];
#pragma unroll
    for (int j = 0; j < 16; j++) acc[j] = 0.f;
    const float* vr = &sm[wave][2][0];
#pragma unroll 4
    for (int t = 0; t < 32; t++) {
        const float wv = wrow[t];
#pragma unroll
        for (int j = 0; j < 16; j++) acc[j] += wv * vr[t * 33 + half * 16 + j];
    }

    // write attn as hi/lo bf16
    u16 hs[16], ls[16];
#pragma unroll
    for (int j = 0; j < 16; j++) {
        hs[j] = f2bf(acc[j]);
        ls[j] = f2bf(acc[j] - bf2f(hs[j]));
    }
    const size_t base = T * HID + h * 32 + half * 16;
    uint32 ph[8], pl[8];
#pragma unroll
    for (int j = 0; j < 8; j++) {
        ph[j] = (uint32)hs[2 * j] | ((uint32)hs[2 * j + 1] << 16);
        pl[j] = (uint32)ls[2 * j] | ((uint32)ls[2 * j + 1] << 16);
    }
    *reinterpret_cast<uint4*>(Ohi + base)     = make_uint4(ph[0], ph[1], ph[2], ph[3]);
    *reinterpret_cast<uint4*>(Ohi + base + 8) = make_uint4(ph[4], ph[5], ph[6], ph[7]);
    *reinterpret_cast<uint4*>(Olo + base)     = make_uint4(pl[0], pl[1], pl[2], pl[3]);
    *reinterpret_cast<uint4*>(Olo + base + 8) = make_uint4(pl[4], pl[5], pl[6], pl[7]);
}

// ---------- KL scalar ----------
__global__ void kl_kernel(const float* __restrict__ mu_q, const float* __restrict__ sigma_q,
                          const float* __restrict__ mu_kv, const float* __restrict__ sigma_kv,
                          float* __restrict__ out) {
    const int l = threadIdx.x;
    float t;
    if (l < 32) {
        t = 1.f + sigma_q[l] - mu_q[l] * mu_q[l] - expf(sigma_q[l]);
    } else {
        const int d = l - 32;
        t = 1.f + sigma_kv[d] - mu_kv[d] * mu_kv[d] - expf(sigma_kv[d]);
    }
    t *= -0.5f / 32.f;
#pragma unroll
    for (int o = 32; o > 0; o >>= 1) t += __shfl_down(t, o);
    if (l == 0) out[0] = t;
}

extern "C" void kernel_launch(void* const* d_in, const int* in_sizes, int n_in,
                              void* d_out, int out_size, void* d_ws, size_t ws_size,
                              hipStream_t stream) {
    const float* hidden   = (const float*)d_in[0];
    const float* wq       = (const float*)d_in[1];
    const float* wk       = (const float*)d_in[2];
    const float* wv       = (const float*)d_in[3];
    const float* wo       = (const float*)d_in[4];
    const float* mu_q     = (const float*)d_in[5];
    const float* sigma_q  = (const float*)d_in[6];
    const float* mu_kv    = (const float*)d_in[7];
    const float* sigma_kv = (const float*)d_in[8];
    const float* eps_q    = (const float*)d_in[9];
    const float* eps_kv   = (const float*)d_in[10];
    float* out = (float*)d_out;

    // ---- workspace-adaptive chunking ----
    // static: 8 weight-split buffers (16 MB). per token (chunk-resident):
    //   xh+xl (bf16, reused as attn hi/lo out): 4 KB; q,k,v fp32: 12 KB -> 16 KB.
    const size_t WN = (size_t)HID * HID;         // elems per weight buffer
    const size_t WBYTES = 8 * WN * 2;            // 16 MB
    int CH = NTOK;                               // tokens per chunk (power of two)
    while (CH > 128 && WBYTES + (size_t)CH * 16384 > ws_size) CH >>= 1;

    char* ws = (char*)d_ws;
    u16* wsp = (u16*)ws;
    u16 *wqh = wsp + 0 * WN, *wql = wsp + 1 * WN;
    u16 *wkh = wsp + 2 * WN, *wkl = wsp + 3 * WN;
    u16 *wvh = wsp + 4 * WN, *wvl = wsp + 5 * WN;
    u16 *woh = wsp + 6 * WN, *wol = wsp + 7 * WN;
    char* dyn = ws + WBYTES;
    u16*   xh = (u16*)dyn;                       // CH*1024 bf16
    u16*   xl = xh + (size_t)CH * HID;
    float* q  = (float*)(xl + (size_t)CH * HID);
    float* k  = q + (size_t)CH * HID;
    float* v  = k + (size_t)CH * HID;

    // weight splits (once)
    split_kernel<<<1024, 256, 0, stream>>>(wq, wqh, wql, HID * HID);
    split_kernel<<<1024, 256, 0, stream>>>(wk, wkh, wkl, HID * HID);
    split_kernel<<<1024, 256, 0, stream>>>(wv, wvh, wvl, HID * HID);
    split_kernel<<<1024, 256, 0, stream>>>(wo, woh, wol, HID * HID);

    const int nchunks = NTOK / CH;
    for (int c = 0; c < nchunks; ++c) {
        const size_t off = (size_t)c * CH * HID;
        // 1) split hidden chunk -> xh/xl
        split_kernel<<<CH, 256, 0, stream>>>(hidden + off, xh, xl, CH * HID);
        // 2) q,k,v projections for chunk
        dim3 gqkv(CH / 128, HID / 128, 3);
        gemm_qkv<<<gqkv, 256, 0, stream>>>(xh, xl, wqh, wql, wkh, wkl, wvh, wvl, q, k, v);
        // 3) per-token attention -> attn hi/lo (reuses xh/xl buffers)
        attn_kernel<<<CH / 4, 256, 0, stream>>>(q, k, v, mu_q, sigma_q, mu_kv, sigma_kv,
                                                eps_q, eps_kv, xh, xl);
        // 4) output projection -> d_out chunk
        dim3 gout(CH / 128, HID / 128, 1);
        gemm_one<<<gout, 256, 0, stream>>>(xh, xl, woh, wol, out + off);
    }

    // 5) KL scalar -> last element of d_out
    kl_kernel<<<1, 64, 0, stream>>>(mu_q, sigma_q, mu_kv, sigma_kv, out + (out_size - 1));
}

// Round 4
// 1323.811 us; speedup vs baseline: 1.0017x; 1.0017x over previous
//
#include <hip/hip_runtime.h>

typedef unsigned int uint32;
typedef unsigned short u16;
typedef __attribute__((ext_vector_type(4))) float f32x4;
typedef __attribute__((ext_vector_type(8))) short bf16x8;

#define HID 1024
#define NTOK 32768  // B*S = 4*8192

// ---------- bf16 helpers (RNE, raw bits; inputs are finite) ----------
__device__ __forceinline__ u16 f2bf(float f) {
    uint32 u = __builtin_bit_cast(uint32, f);
    u += 0x7FFFu + ((u >> 16) & 1u);
    return (u16)(u >> 16);
}
__device__ __forceinline__ float bf2f(u16 h) {
    uint32 u = ((uint32)h) << 16;
    return __builtin_bit_cast(float, u);
}

// async global->LDS, 16B per lane, LDS dest = wave-uniform base + lane*16
__device__ __forceinline__ void async16(const void* g, void* l) {
    __builtin_amdgcn_global_load_lds(
        (const __attribute__((address_space(1))) uint32*)g,
        (__attribute__((address_space(3))) uint32*)l, 16, 0, 0);
}

// ---------- fp32 -> (hi,lo) bf16 split, 4 elems/thread ----------
__global__ __launch_bounds__(256) void split_kernel(const float* __restrict__ x,
                                                    u16* __restrict__ hi,
                                                    u16* __restrict__ lo,
                                                    int n) {
    int i = (blockIdx.x * 256 + threadIdx.x) * 4;
    if (i >= n) return;
    float4 v = *reinterpret_cast<const float4*>(x + i);
    u16 h0 = f2bf(v.x), h1 = f2bf(v.y), h2 = f2bf(v.z), h3 = f2bf(v.w);
    u16 l0 = f2bf(v.x - bf2f(h0)), l1 = f2bf(v.y - bf2f(h1));
    u16 l2 = f2bf(v.z - bf2f(h2)), l3 = f2bf(v.w - bf2f(h3));
    *reinterpret_cast<uint2*>(hi + i) =
        make_uint2((uint32)h0 | ((uint32)h1 << 16), (uint32)h2 | ((uint32)h3 << 16));
    *reinterpret_cast<uint2*>(lo + i) =
        make_uint2((uint32)l0 | ((uint32)l1 << 16), (uint32)l2 | ((uint32)l3 << 16));
}

// ---------- split-bf16 GEMM: C[m,n] = sum_k A[m,k]*W[n,k] (fp32 out) ----------
// A: [M][1024] hi/lo bf16, W: [1024][1024] hi/lo bf16 (row n = output col n)
// 128x128 tile, BK=32, 4 waves, each wave 64x64 (4x4 frags of 16x16x32 MFMA)
// LDS tiles use a T2-style XOR swizzle (granule g -> g ^ ((g>>3)&3)) applied on
// BOTH the global-source side (pre-swizzled per-lane address, LDS dest linear
// per rule #21) and the ds_read side. Bank-group coverage is exactly 2-way
// (free). Bit-exact vs the unswizzled version.
__device__ __forceinline__ void gemm_body(const u16* __restrict__ Ahi,
                                          const u16* __restrict__ Alo,
                                          const u16* __restrict__ Bhi,
                                          const u16* __restrict__ Blo,
                                          float* __restrict__ C) {
    __shared__ u16 sAh[128 * 32], sAl[128 * 32], sBh[128 * 32], sBl[128 * 32];
    const int tid = threadIdx.x;
    const int wave = tid >> 6, lane = tid & 63;
    const int m0 = blockIdx.x * 128, n0 = blockIdx.y * 128;
    const int wm = (wave >> 1) * 64, wn = (wave & 1) * 64;
    const int srow = lane >> 2;                               // 0..15 staging row in segment
    const int scol = ((lane & 3) ^ ((lane >> 3) & 3)) * 8;    // swizzled source k-slot
    const int fr = lane & 15;                                 // fragment row/col
    const int ks = (((lane >> 4) ^ ((lane >> 1) & 3)) & 3) * 8;  // swizzled LDS k-slot

    f32x4 acc[4][4];
#pragma unroll
    for (int a = 0; a < 4; a++)
#pragma unroll
        for (int b = 0; b < 4; b++) acc[a][b] = f32x4{0.f, 0.f, 0.f, 0.f};

    for (int k0 = 0; k0 < HID; k0 += 32) {
        // stage 4 tiles (A hi/lo, B hi/lo), each 128x32 bf16; wave w does segments 2w,2w+1
#pragma unroll
        for (int i = 0; i < 2; i++) {
            const int seg = wave * 2 + i;
            const int r = seg * 16 + srow;
            const size_t ga = (size_t)(m0 + r) * HID + k0 + scol;
            const size_t gb = (size_t)(n0 + r) * HID + k0 + scol;
            async16(Ahi + ga, &sAh[seg * 512]);
            async16(Alo + ga, &sAl[seg * 512]);
            async16(Bhi + gb, &sBh[seg * 512]);
            async16(Blo + gb, &sBl[seg * 512]);
        }
        __syncthreads();  // drains vmcnt per guide, then barrier

        bf16x8 fah[4], fal[4], fbh[4], fbl[4];
#pragma unroll
        for (int a = 0; a < 4; a++) {
            const int row = wm + a * 16 + fr;
            fah[a] = *reinterpret_cast<const bf16x8*>(&sAh[row * 32 + ks]);
            fal[a] = *reinterpret_cast<const bf16x8*>(&sAl[row * 32 + ks]);
        }
#pragma unroll
        for (int b = 0; b < 4; b++) {
            const int row = wn + b * 16 + fr;
            fbh[b] = *reinterpret_cast<const bf16x8*>(&sBh[row * 32 + ks]);
            fbl[b] = *reinterpret_cast<const bf16x8*>(&sBl[row * 32 + ks]);
        }
        // product 1: Ahi*Bhi
#pragma unroll
        for (int a = 0; a < 4; a++)
#pragma unroll
            for (int b = 0; b < 4; b++)
                acc[a][b] = __builtin_amdgcn_mfma_f32_16x16x32_bf16(fah[a], fbh[b], acc[a][b], 0, 0, 0);
        // product 2: Ahi*Blo
#pragma unroll
        for (int a = 0; a < 4; a++)
#pragma unroll
            for (int b = 0; b < 4; b++)
                acc[a][b] = __builtin_amdgcn_mfma_f32_16x16x32_bf16(fah[a], fbl[b], acc[a][b], 0, 0, 0);
        // product 3: Alo*Bhi
#pragma unroll
        for (int a = 0; a < 4; a++)
#pragma unroll
            for (int b = 0; b < 4; b++)
                acc[a][b] = __builtin_amdgcn_mfma_f32_16x16x32_bf16(fal[a], fbh[b], acc[a][b], 0, 0, 0);
        __syncthreads();
    }

    // epilogue: D col = lane&15, row = (lane>>4)*4 + j  [verified m89/m91]
    const int col = lane & 15, r0 = (lane >> 4) * 4;
#pragma unroll
    for (int a = 0; a < 4; a++)
#pragma unroll
        for (int b = 0; b < 4; b++)
#pragma unroll
            for (int j = 0; j < 4; j++)
                C[(size_t)(m0 + wm + a * 16 + r0 + j) * HID + (n0 + wn + b * 16 + col)] =
                    acc[a][b][j];
}

__global__ __launch_bounds__(256) void gemm_qkv(
    const u16* __restrict__ xhi, const u16* __restrict__ xlo,
    const u16* __restrict__ w0h, const u16* __restrict__ w0l,
    const u16* __restrict__ w1h, const u16* __restrict__ w1l,
    const u16* __restrict__ w2h, const u16* __restrict__ w2l,
    float* __restrict__ q, float* __restrict__ k, float* __restrict__ v) {
    const u16 *bh, *bl;
    float* c;
    if (blockIdx.z == 0)      { bh = w0h; bl = w0l; c = q; }
    else if (blockIdx.z == 1) { bh = w1h; bl = w1l; c = k; }
    else                      { bh = w2h; bl = w2l; c = v; }
    gemm_body(xhi, xlo, bh, bl, c);
}

__global__ __launch_bounds__(256) void gemm_one(
    const u16* __restrict__ ahi, const u16* __restrict__ alo,
    const u16* __restrict__ bh, const u16* __restrict__ bl,
    float* __restrict__ c) {
    gemm_body(ahi, alo, bh, bl, c);
}

// ---------- per-token 32x32 attention (fp32), masks fused, writes attn hi/lo bf16 ----------
// 4 waves/block, 1 token/wave. Lane = 2*h + half; half covers 16 t (scores) / 16 d (PV).
__global__ __launch_bounds__(256) void attn_kernel(
    const float* __restrict__ Q, const float* __restrict__ K, const float* __restrict__ V,
    const float* __restrict__ mu_q, const float* __restrict__ sigma_q,
    const float* __restrict__ mu_kv, const float* __restrict__ sigma_kv,
    const float* __restrict__ eps_q, const float* __restrict__ eps_kv,
    u16* __restrict__ Ohi, u16* __restrict__ Olo) {
    // mat 0: q (reused as softmax weights after q consumed), 1: k, 2: v
    __shared__ float sm[4][3][32 * 33];
    __shared__ float mq[32], mkv[32];
    const int tid = threadIdx.x, wave = tid >> 6, lane = tid & 63;

    if (tid < 32) {
        mq[tid] = 1.f / (1.f + __expf(-(mu_q[tid] + eps_q[tid] * sigma_q[tid])));
    } else if (tid < 64) {
        const int d = tid - 32;
        mkv[d] = 1.f / (1.f + __expf(-(mu_kv[d] + eps_kv[d] * sigma_kv[d])));
    }
    __syncthreads();

    const size_t T = (size_t)blockIdx.x * 4 + wave;
    const float* src0 = Q + T * HID;
    const float* src1 = K + T * HID;
    const float* src2 = V + T * HID;
#pragma unroll
    for (int m = 0; m < 3; m++) {
        const float* s = (m == 0) ? src0 : (m == 1) ? src1 : src2;
        const float* msk = (m == 0) ? mq : mkv;
#pragma unroll
        for (int i = 0; i < 4; i++) {
            const int e = (i * 64 + lane) * 4;
            float4 v4 = *reinterpret_cast<const float4*>(s + e);
            const int r = e >> 5, c = e & 31;
            float* dst = &sm[wave][m][r * 33 + c];
            dst[0] = v4.x * msk[c];
            dst[1] = v4.y * msk[c + 1];
            dst[2] = v4.z * msk[c + 2];
            dst[3] = v4.w * msk[c + 3];
        }
    }
    __syncthreads();

    const int h = lane >> 1, half = lane & 1;
    // q row into registers (then sm[wave][0] is reusable for weights)
    float qreg[32];
    const float* qr = &sm[wave][0][h * 33];
#pragma unroll
    for (int d = 0; d < 32; d++) qreg[d] = qr[d];

    // scores for 16 t's
    float sc[16];
    const float* kr = &sm[wave][1][0];
#pragma unroll
    for (int t1 = 0; t1 < 16; t1++) {
        const int t = half * 16 + t1;
        float a = 0.f;
#pragma unroll
        for (int d = 0; d < 32; d++) a += qreg[d] * kr[t * 33 + d];
        sc[t1] = a * 0.17677669529663687f;  // 1/sqrt(32)
    }
    // softmax over 32 t (2 lanes per row)
    float mx = sc[0];
#pragma unroll
    for (int t1 = 1; t1 < 16; t1++) mx = fmaxf(mx, sc[t1]);
    mx = fmaxf(mx, __shfl_xor(mx, 1));
    float sum = 0.f;
#pragma unroll
    for (int t1 = 0; t1 < 16; t1++) {
        sc[t1] = __expf(sc[t1] - mx);
        sum += sc[t1];
    }
    sum += __shfl_xor(sum, 1);
    const float inv = 1.f / sum;
    float* wrow = &sm[wave][0][h * 33];
#pragma unroll
    for (int t1 = 0; t1 < 16; t1++) wrow[half * 16 + t1] = sc[t1] * inv;
    __syncthreads();

    // PV: attn[h][d] = sum_t w[h][t] * v[t][d], this lane: d in [half*16, half*16+16)
    float acc[16];
#pragma unroll
    for (int j = 0; j < 16; j++) acc[j] = 0.f;
    const float* vr = &sm[wave][2][0];
#pragma unroll 4
    for (int t = 0; t < 32; t++) {
        const float wv = wrow[t];
#pragma unroll
        for (int j = 0; j < 16; j++) acc[j] += wv * vr[t * 33 + half * 16 + j];
    }

    // write attn as hi/lo bf16
    u16 hs[16], ls[16];
#pragma unroll
    for (int j = 0; j < 16; j++) {
        hs[j] = f2bf(acc[j]);
        ls[j] = f2bf(acc[j] - bf2f(hs[j]));
    }
    const size_t base = T * HID + h * 32 + half * 16;
    uint32 ph[8], pl[8];
#pragma unroll
    for (int j = 0; j < 8; j++) {
        ph[j] = (uint32)hs[2 * j] | ((uint32)hs[2 * j + 1] << 16);
        pl[j] = (uint32)ls[2 * j] | ((uint32)ls[2 * j + 1] << 16);
    }
    *reinterpret_cast<uint4*>(Ohi + base)     = make_uint4(ph[0], ph[1], ph[2], ph[3]);
    *reinterpret_cast<uint4*>(Ohi + base + 8) = make_uint4(ph[4], ph[5], ph[6], ph[7]);
    *reinterpret_cast<uint4*>(Olo + base)     = make_uint4(pl[0], pl[1], pl[2], pl[3]);
    *reinterpret_cast<uint4*>(Olo + base + 8) = make_uint4(pl[4], pl[5], pl[6], pl[7]);
}

// ---------- KL scalar ----------
__global__ void kl_kernel(const float* __restrict__ mu_q, const float* __restrict__ sigma_q,
                          const float* __restrict__ mu_kv, const float* __restrict__ sigma_kv,
                          float* __restrict__ out) {
    const int l = threadIdx.x;
    float t;
    if (l < 32) {
        t = 1.f + sigma_q[l] - mu_q[l] * mu_q[l] - expf(sigma_q[l]);
    } else {
        const int d = l - 32;
        t = 1.f + sigma_kv[d] - mu_kv[d] * mu_kv[d] - expf(sigma_kv[d]);
    }
    t *= -0.5f / 32.f;
#pragma unroll
    for (int o = 32; o > 0; o >>= 1) t += __shfl_down(t, o);
    if (l == 0) out[0] = t;
}

extern "C" void kernel_launch(void* const* d_in, const int* in_sizes, int n_in,
                              void* d_out, int out_size, void* d_ws, size_t ws_size,
                              hipStream_t stream) {
    const float* hidden   = (const float*)d_in[0];
    const float* wq       = (const float*)d_in[1];
    const float* wk       = (const float*)d_in[2];
    const float* wv       = (const float*)d_in[3];
    const float* wo       = (const float*)d_in[4];
    const float* mu_q     = (const float*)d_in[5];
    const float* sigma_q  = (const float*)d_in[6];
    const float* mu_kv    = (const float*)d_in[7];
    const float* sigma_kv = (const float*)d_in[8];
    const float* eps_q    = (const float*)d_in[9];
    const float* eps_kv   = (const float*)d_in[10];
    float* out = (float*)d_out;

    // ---- workspace-adaptive chunking ----
    // static: 8 weight-split buffers (16 MB). per token (chunk-resident):
    //   xh+xl (bf16, reused as attn hi/lo out): 4 KB; q,k,v fp32: 12 KB -> 16 KB.
    const size_t WN = (size_t)HID * HID;         // elems per weight buffer
    const size_t WBYTES = 8 * WN * 2;            // 16 MB
    int CH = NTOK;                               // tokens per chunk (power of two)
    while (CH > 128 && WBYTES + (size_t)CH * 16384 > ws_size) CH >>= 1;

    char* ws = (char*)d_ws;
    u16* wsp = (u16*)ws;
    u16 *wqh = wsp + 0 * WN, *wql = wsp + 1 * WN;
    u16 *wkh = wsp + 2 * WN, *wkl = wsp + 3 * WN;
    u16 *wvh = wsp + 4 * WN, *wvl = wsp + 5 * WN;
    u16 *woh = wsp + 6 * WN, *wol = wsp + 7 * WN;
    char* dyn = ws + WBYTES;
    u16*   xh = (u16*)dyn;                       // CH*1024 bf16
    u16*   xl = xh + (size_t)CH * HID;
    float* q  = (float*)(xl + (size_t)CH * HID);
    float* k  = q + (size_t)CH * HID;
    float* v  = k + (size_t)CH * HID;

    // weight splits (once)
    split_kernel<<<1024, 256, 0, stream>>>(wq, wqh, wql, HID * HID);
    split_kernel<<<1024, 256, 0, stream>>>(wk, wkh, wkl, HID * HID);
    split_kernel<<<1024, 256, 0, stream>>>(wv, wvh, wvl, HID * HID);
    split_kernel<<<1024, 256, 0, stream>>>(wo, woh, wol, HID * HID);

    const int nchunks = NTOK / CH;
    for (int c = 0; c < nchunks; ++c) {
        const size_t off = (size_t)c * CH * HID;
        // 1) split hidden chunk -> xh/xl
        split_kernel<<<CH, 256, 0, stream>>>(hidden + off, xh, xl, CH * HID);
        // 2) q,k,v projections for chunk
        dim3 gqkv(CH / 128, HID / 128, 3);
        gemm_qkv<<<gqkv, 256, 0, stream>>>(xh, xl, wqh, wql, wkh, wkl, wvh, wvl, q, k, v);
        // 3) per-token attention -> attn hi/lo (reuses xh/xl buffers)
        attn_kernel<<<CH / 4, 256, 0, stream>>>(q, k, v, mu_q, sigma_q, mu_kv, sigma_kv,
                                                eps_q, eps_kv, xh, xl);
        // 4) output projection -> d_out chunk
        dim3 gout(CH / 128, HID / 128, 1);
        gemm_one<<<gout, 256, 0, stream>>>(xh, xl, woh, wol, out + off);
    }

    // 5) KL scalar -> last element of d_out
    kl_kernel<<<1, 64, 0, stream>>>(mu_q, sigma_q, mu_kv, sigma_kv, out + (out_size - 1));
}

// Round 5
// 1218.483 us; speedup vs baseline: 1.0883x; 1.0864x over previous
//
#include <hip/hip_runtime.h>

typedef unsigned int uint32;
typedef unsigned short u16;
typedef __attribute__((ext_vector_type(4))) float f32x4;
typedef __attribute__((ext_vector_type(8))) short bf16x8;

#define HID 1024
#define NTOK 32768  // B*S = 4*8192

// ---------- bf16 helpers (RNE, raw bits; inputs are finite) ----------
__device__ __forceinline__ u16 f2bf(float f) {
    uint32 u = __builtin_bit_cast(uint32, f);
    u += 0x7FFFu + ((u >> 16) & 1u);
    return (u16)(u >> 16);
}
__device__ __forceinline__ float bf2f(u16 h) {
    uint32 u = ((uint32)h) << 16;
    return __builtin_bit_cast(float, u);
}

// async global->LDS, 16B per lane, LDS dest = wave-uniform base + lane*16
__device__ __forceinline__ void async16(const void* g, void* l) {
    __builtin_amdgcn_global_load_lds(
        (const __attribute__((address_space(1))) uint32*)g,
        (__attribute__((address_space(3))) uint32*)l, 16, 0, 0);
}

// ---------- fp32 -> (hi,lo) bf16 split, 4 elems/thread ----------
__global__ __launch_bounds__(256) void split_kernel(const float* __restrict__ x,
                                                    u16* __restrict__ hi,
                                                    u16* __restrict__ lo,
                                                    int n) {
    int i = (blockIdx.x * 256 + threadIdx.x) * 4;
    if (i >= n) return;
    float4 v = *reinterpret_cast<const float4*>(x + i);
    u16 h0 = f2bf(v.x), h1 = f2bf(v.y), h2 = f2bf(v.z), h3 = f2bf(v.w);
    u16 l0 = f2bf(v.x - bf2f(h0)), l1 = f2bf(v.y - bf2f(h1));
    u16 l2 = f2bf(v.z - bf2f(h2)), l3 = f2bf(v.w - bf2f(h3));
    *reinterpret_cast<uint2*>(hi + i) =
        make_uint2((uint32)h0 | ((uint32)h1 << 16), (uint32)h2 | ((uint32)h3 << 16));
    *reinterpret_cast<uint2*>(lo + i) =
        make_uint2((uint32)l0 | ((uint32)l1 << 16), (uint32)l2 | ((uint32)l3 << 16));
}

// ---------- split-bf16 GEMM: C[m,n] = sum_k A[m,k]*W[n,k] (fp32 out) ----------
// 128x128 tile, BK=32, 4 waves, each wave 64x64 (4x4 frags of 16x16x32 MFMA).
// T2 both-sides XOR swizzle (verified r4: SQ_LDS_BANK_CONFLICT == 0, bit-exact).
// T3 minimum 2-phase pipeline: double-buffered LDS; per K-step issue next-tile
// global_load_lds BEFORE ds_read+MFMA of current tile; single __syncthreads
// (vmcnt(0) drain) after MFMA so prefetch latency hides under compute.
// T5 setprio(1) around the MFMA cluster.
__device__ __forceinline__ void gemm_body(const u16* __restrict__ Ahi,
                                          const u16* __restrict__ Alo,
                                          const u16* __restrict__ Bhi,
                                          const u16* __restrict__ Blo,
                                          float* __restrict__ C) {
    __shared__ u16 sAh[2][128 * 32], sAl[2][128 * 32];
    __shared__ u16 sBh[2][128 * 32], sBl[2][128 * 32];
    const int tid = threadIdx.x;
    const int wave = tid >> 6, lane = tid & 63;
    const int m0 = blockIdx.x * 128, n0 = blockIdx.y * 128;
    const int wm = (wave >> 1) * 64, wn = (wave & 1) * 64;
    const int srow = lane >> 2;                               // staging row in segment
    const int scol = ((lane & 3) ^ ((lane >> 3) & 3)) * 8;    // swizzled source k-slot
    const int fr = lane & 15;                                 // fragment row/col
    const int ks = (((lane >> 4) ^ ((lane >> 1) & 3)) & 3) * 8;  // swizzled LDS k-slot

    const int seg0 = wave * 2, seg1 = wave * 2 + 1;
    const int r0g = seg0 * 16 + srow, r1g = seg1 * 16 + srow;

    f32x4 acc[4][4];
#pragma unroll
    for (int a = 0; a < 4; a++)
#pragma unroll
        for (int b = 0; b < 4; b++) acc[a][b] = f32x4{0.f, 0.f, 0.f, 0.f};

    // prologue: stage k0=0 into buf 0
    {
        const size_t ga0 = (size_t)(m0 + r0g) * HID + scol;
        const size_t ga1 = (size_t)(m0 + r1g) * HID + scol;
        const size_t gb0 = (size_t)(n0 + r0g) * HID + scol;
        const size_t gb1 = (size_t)(n0 + r1g) * HID + scol;
        async16(Ahi + ga0, &sAh[0][seg0 * 512]);
        async16(Ahi + ga1, &sAh[0][seg1 * 512]);
        async16(Alo + ga0, &sAl[0][seg0 * 512]);
        async16(Alo + ga1, &sAl[0][seg1 * 512]);
        async16(Bhi + gb0, &sBh[0][seg0 * 512]);
        async16(Bhi + gb1, &sBh[0][seg1 * 512]);
        async16(Blo + gb0, &sBl[0][seg0 * 512]);
        async16(Blo + gb1, &sBl[0][seg1 * 512]);
    }
    __syncthreads();

    int cur = 0;
    for (int k0 = 0; k0 < HID; k0 += 32) {
        // prefetch next K-tile into the other buffer (skipped on last iter)
        if (k0 + 32 < HID) {
            const int nxt = cur ^ 1;
            const size_t ga0 = (size_t)(m0 + r0g) * HID + (k0 + 32) + scol;
            const size_t ga1 = (size_t)(m0 + r1g) * HID + (k0 + 32) + scol;
            const size_t gb0 = (size_t)(n0 + r0g) * HID + (k0 + 32) + scol;
            const size_t gb1 = (size_t)(n0 + r1g) * HID + (k0 + 32) + scol;
            async16(Ahi + ga0, &sAh[nxt][seg0 * 512]);
            async16(Ahi + ga1, &sAh[nxt][seg1 * 512]);
            async16(Alo + ga0, &sAl[nxt][seg0 * 512]);
            async16(Alo + ga1, &sAl[nxt][seg1 * 512]);
            async16(Bhi + gb0, &sBh[nxt][seg0 * 512]);
            async16(Bhi + gb1, &sBh[nxt][seg1 * 512]);
            async16(Blo + gb0, &sBl[nxt][seg0 * 512]);
            async16(Blo + gb1, &sBl[nxt][seg1 * 512]);
        }

        bf16x8 fah[4], fal[4], fbh[4], fbl[4];
#pragma unroll
        for (int a = 0; a < 4; a++) {
            const int row = wm + a * 16 + fr;
            fah[a] = *reinterpret_cast<const bf16x8*>(&sAh[cur][row * 32 + ks]);
            fal[a] = *reinterpret_cast<const bf16x8*>(&sAl[cur][row * 32 + ks]);
        }
#pragma unroll
        for (int b = 0; b < 4; b++) {
            const int row = wn + b * 16 + fr;
            fbh[b] = *reinterpret_cast<const bf16x8*>(&sBh[cur][row * 32 + ks]);
            fbl[b] = *reinterpret_cast<const bf16x8*>(&sBl[cur][row * 32 + ks]);
        }

        __builtin_amdgcn_s_setprio(1);
        // product 1: Ahi*Bhi
#pragma unroll
        for (int a = 0; a < 4; a++)
#pragma unroll
            for (int b = 0; b < 4; b++)
                acc[a][b] = __builtin_amdgcn_mfma_f32_16x16x32_bf16(fah[a], fbh[b], acc[a][b], 0, 0, 0);
        // product 2: Ahi*Blo
#pragma unroll
        for (int a = 0; a < 4; a++)
#pragma unroll
            for (int b = 0; b < 4; b++)
                acc[a][b] = __builtin_amdgcn_mfma_f32_16x16x32_bf16(fah[a], fbl[b], acc[a][b], 0, 0, 0);
        // product 3: Alo*Bhi
#pragma unroll
        for (int a = 0; a < 4; a++)
#pragma unroll
            for (int b = 0; b < 4; b++)
                acc[a][b] = __builtin_amdgcn_mfma_f32_16x16x32_bf16(fal[a], fbh[b], acc[a][b], 0, 0, 0);
        __builtin_amdgcn_s_setprio(0);

        // one barrier per K-step: (a) vmcnt(0) drain completes the prefetch
        // issued above (covered by the MFMA phase), (b) all waves done reading
        // buf[cur] so next iter may overwrite it.
        __syncthreads();
        cur ^= 1;
    }

    // epilogue: D col = lane&15, row = (lane>>4)*4 + j  [verified m89/m91]
    const int col = lane & 15, rr = (lane >> 4) * 4;
#pragma unroll
    for (int a = 0; a < 4; a++)
#pragma unroll
        for (int b = 0; b < 4; b++)
#pragma unroll
            for (int j = 0; j < 4; j++)
                C[(size_t)(m0 + wm + a * 16 + rr + j) * HID + (n0 + wn + b * 16 + col)] =
                    acc[a][b][j];
}

__global__ __launch_bounds__(256) void gemm_qkv(
    const u16* __restrict__ xhi, const u16* __restrict__ xlo,
    const u16* __restrict__ w0h, const u16* __restrict__ w0l,
    const u16* __restrict__ w1h, const u16* __restrict__ w1l,
    const u16* __restrict__ w2h, const u16* __restrict__ w2l,
    float* __restrict__ q, float* __restrict__ k, float* __restrict__ v) {
    const u16 *bh, *bl;
    float* c;
    if (blockIdx.z == 0)      { bh = w0h; bl = w0l; c = q; }
    else if (blockIdx.z == 1) { bh = w1h; bl = w1l; c = k; }
    else                      { bh = w2h; bl = w2l; c = v; }
    gemm_body(xhi, xlo, bh, bl, c);
}

__global__ __launch_bounds__(256) void gemm_one(
    const u16* __restrict__ ahi, const u16* __restrict__ alo,
    const u16* __restrict__ bh, const u16* __restrict__ bl,
    float* __restrict__ c) {
    gemm_body(ahi, alo, bh, bl, c);
}

// ---------- per-token 32x32 attention (fp32), masks fused, writes attn hi/lo bf16 ----------
// 4 waves/block, 1 token/wave. Lane = 2*h + half; half covers 16 t (scores) / 16 d (PV).
__global__ __launch_bounds__(256) void attn_kernel(
    const float* __restrict__ Q, const float* __restrict__ K, const float* __restrict__ V,
    const float* __restrict__ mu_q, const float* __restrict__ sigma_q,
    const float* __restrict__ mu_kv, const float* __restrict__ sigma_kv,
    const float* __restrict__ eps_q, const float* __restrict__ eps_kv,
    u16* __restrict__ Ohi, u16* __restrict__ Olo) {
    // mat 0: q (reused as softmax weights after q consumed), 1: k, 2: v
    __shared__ float sm[4][3][32 * 33];
    __shared__ float mq[32], mkv[32];
    const int tid = threadIdx.x, wave = tid >> 6, lane = tid & 63;

    if (tid < 32) {
        mq[tid] = 1.f / (1.f + __expf(-(mu_q[tid] + eps_q[tid] * sigma_q[tid])));
    } else if (tid < 64) {
        const int d = tid - 32;
        mkv[d] = 1.f / (1.f + __expf(-(mu_kv[d] + eps_kv[d] * sigma_kv[d])));
    }
    __syncthreads();

    const size_t T = (size_t)blockIdx.x * 4 + wave;
    const float* src0 = Q + T * HID;
    const float* src1 = K + T * HID;
    const float* src2 = V + T * HID;
#pragma unroll
    for (int m = 0; m < 3; m++) {
        const float* s = (m == 0) ? src0 : (m == 1) ? src1 : src2;
        const float* msk = (m == 0) ? mq : mkv;
#pragma unroll
        for (int i = 0; i < 4; i++) {
            const int e = (i * 64 + lane) * 4;
            float4 v4 = *reinterpret_cast<const float4*>(s + e);
            const int r = e >> 5, c = e & 31;
            float* dst = &sm[wave][m][r * 33 + c];
            dst[0] = v4.x * msk[c];
            dst[1] = v4.y * msk[c + 1];
            dst[2] = v4.z * msk[c + 2];
            dst[3] = v4.w * msk[c + 3];
        }
    }
    __syncthreads();

    const int h = lane >> 1, half = lane & 1;
    // q row into registers (then sm[wave][0] is reusable for weights)
    float qreg[32];
    const float* qr = &sm[wave][0][h * 33];
#pragma unroll
    for (int d = 0; d < 32; d++) qreg[d] = qr[d];

    // scores for 16 t's
    float sc[16];
    const float* kr = &sm[wave][1][0];
#pragma unroll
    for (int t1 = 0; t1 < 16; t1++) {
        const int t = half * 16 + t1;
        float a = 0.f;
#pragma unroll
        for (int d = 0; d < 32; d++) a += qreg[d] * kr[t * 33 + d];
        sc[t1] = a * 0.17677669529663687f;  // 1/sqrt(32)
    }
    // softmax over 32 t (2 lanes per row)
    float mx = sc[0];
#pragma unroll
    for (int t1 = 1; t1 < 16; t1++) mx = fmaxf(mx, sc[t1]);
    mx = fmaxf(mx, __shfl_xor(mx, 1));
    float sum = 0.f;
#pragma unroll
    for (int t1 = 0; t1 < 16; t1++) {
        sc[t1] = __expf(sc[t1] - mx);
        sum += sc[t1];
    }
    sum += __shfl_xor(sum, 1);
    const float inv = 1.f / sum;
    float* wrow = &sm[wave][0][h * 33];
#pragma unroll
    for (int t1 = 0; t1 < 16; t1++) wrow[half * 16 + t1] = sc[t1] * inv;
    __syncthreads();

    // PV: attn[h][d] = sum_t w[h][t] * v[t][d], this lane: d in [half*16, half*16+16)
    float acc[16];
#pragma unroll
    for (int j = 0; j < 16; j++) acc[j] = 0.f;
    const float* vr = &sm[wave][2][0];
#pragma unroll 4
    for (int t = 0; t < 32; t++) {
        const float wv = wrow[t];
#pragma unroll
        for (int j = 0; j < 16; j++) acc[j] += wv * vr[t * 33 + half * 16 + j];
    }

    // write attn as hi/lo bf16
    u16 hs[16], ls[16];
#pragma unroll
    for (int j = 0; j < 16; j++) {
        hs[j] = f2bf(acc[j]);
        ls[j] = f2bf(acc[j] - bf2f(hs[j]));
    }
    const size_t base = T * HID + h * 32 + half * 16;
    uint32 ph[8], pl[8];
#pragma unroll
    for (int j = 0; j < 8; j++) {
        ph[j] = (uint32)hs[2 * j] | ((uint32)hs[2 * j + 1] << 16);
        pl[j] = (uint32)ls[2 * j] | ((uint32)ls[2 * j + 1] << 16);
    }
    *reinterpret_cast<uint4*>(Ohi + base)     = make_uint4(ph[0], ph[1], ph[2], ph[3]);
    *reinterpret_cast<uint4*>(Ohi + base + 8) = make_uint4(ph[4], ph[5], ph[6], ph[7]);
    *reinterpret_cast<uint4*>(Olo + base)     = make_uint4(pl[0], pl[1], pl[2], pl[3]);
    *reinterpret_cast<uint4*>(Olo + base + 8) = make_uint4(pl[4], pl[5], pl[6], pl[7]);
}

// ---------- KL scalar ----------
__global__ void kl_kernel(const float* __restrict__ mu_q, const float* __restrict__ sigma_q,
                          const float* __restrict__ mu_kv, const float* __restrict__ sigma_kv,
                          float* __restrict__ out) {
    const int l = threadIdx.x;
    float t;
    if (l < 32) {
        t = 1.f + sigma_q[l] - mu_q[l] * mu_q[l] - expf(sigma_q[l]);
    } else {
        const int d = l - 32;
        t = 1.f + sigma_kv[d] - mu_kv[d] * mu_kv[d] - expf(sigma_kv[d]);
    }
    t *= -0.5f / 32.f;
#pragma unroll
    for (int o = 32; o > 0; o >>= 1) t += __shfl_down(t, o);
    if (l == 0) out[0] = t;
}

extern "C" void kernel_launch(void* const* d_in, const int* in_sizes, int n_in,
                              void* d_out, int out_size, void* d_ws, size_t ws_size,
                              hipStream_t stream) {
    const float* hidden   = (const float*)d_in[0];
    const float* wq       = (const float*)d_in[1];
    const float* wk       = (const float*)d_in[2];
    const float* wv       = (const float*)d_in[3];
    const float* wo       = (const float*)d_in[4];
    const float* mu_q     = (const float*)d_in[5];
    const float* sigma_q  = (const float*)d_in[6];
    const float* mu_kv    = (const float*)d_in[7];
    const float* sigma_kv = (const float*)d_in[8];
    const float* eps_q    = (const float*)d_in[9];
    const float* eps_kv   = (const float*)d_in[10];
    float* out = (float*)d_out;

    // ---- workspace-adaptive chunking ----
    // static: 8 weight-split buffers (16 MB). per token (chunk-resident):
    //   xh+xl (bf16, reused as attn hi/lo out): 4 KB; q,k,v fp32: 12 KB -> 16 KB.
    const size_t WN = (size_t)HID * HID;         // elems per weight buffer
    const size_t WBYTES = 8 * WN * 2;            // 16 MB
    int CH = NTOK;                               // tokens per chunk (power of two)
    while (CH > 128 && WBYTES + (size_t)CH * 16384 > ws_size) CH >>= 1;

    char* ws = (char*)d_ws;
    u16* wsp = (u16*)ws;
    u16 *wqh = wsp + 0 * WN, *wql = wsp + 1 * WN;
    u16 *wkh = wsp + 2 * WN, *wkl = wsp + 3 * WN;
    u16 *wvh = wsp + 4 * WN, *wvl = wsp + 5 * WN;
    u16 *woh = wsp + 6 * WN, *wol = wsp + 7 * WN;
    char* dyn = ws + WBYTES;
    u16*   xh = (u16*)dyn;                       // CH*1024 bf16
    u16*   xl = xh + (size_t)CH * HID;
    float* q  = (float*)(xl + (size_t)CH * HID);
    float* k  = q + (size_t)CH * HID;
    float* v  = k + (size_t)CH * HID;

    // weight splits (once)
    split_kernel<<<1024, 256, 0, stream>>>(wq, wqh, wql, HID * HID);
    split_kernel<<<1024, 256, 0, stream>>>(wk, wkh, wkl, HID * HID);
    split_kernel<<<1024, 256, 0, stream>>>(wv, wvh, wvl, HID * HID);
    split_kernel<<<1024, 256, 0, stream>>>(wo, woh, wol, HID * HID);

    const int nchunks = NTOK / CH;
    for (int c = 0; c < nchunks; ++c) {
        const size_t off = (size_t)c * CH * HID;
        // 1) split hidden chunk -> xh/xl
        split_kernel<<<CH, 256, 0, stream>>>(hidden + off, xh, xl, CH * HID);
        // 2) q,k,v projections for chunk
        dim3 gqkv(CH / 128, HID / 128, 3);
        gemm_qkv<<<gqkv, 256, 0, stream>>>(xh, xl, wqh, wql, wkh, wkl, wvh, wvl, q, k, v);
        // 3) per-token attention -> attn hi/lo (reuses xh/xl buffers)
        attn_kernel<<<CH / 4, 256, 0, stream>>>(q, k, v, mu_q, sigma_q, mu_kv, sigma_kv,
                                                eps_q, eps_kv, xh, xl);
        // 4) output projection -> d_out chunk
        dim3 gout(CH / 128, HID / 128, 1);
        gemm_one<<<gout, 256, 0, stream>>>(xh, xl, woh, wol, out + off);
    }

    // 5) KL scalar -> last element of d_out
    kl_kernel<<<1, 64, 0, stream>>>(mu_q, sigma_q, mu_kv, sigma_kv, out + (out_size - 1));
}